// Round 1
// baseline (2555.494 us; speedup 1.0000x reference)
//
#include <hip/hip_runtime.h>
#include <cstdint>
#include <cstddef>

#define HN_ 2304
#define G4_ 9216

__device__ __forceinline__ float bf2f(unsigned short u) {
  union { unsigned int i; float f; } v; v.i = ((unsigned int)u) << 16; return v.f;
}
__device__ __forceinline__ unsigned short f2bf(float x) {
  union { float f; unsigned int i; } v; v.f = x;
  unsigned int r = (v.i + 0x7fffu + ((v.i >> 16) & 1u)) >> 16;
  return (unsigned short)r;
}
__device__ __forceinline__ void load4w(const float* p, float& a, float& b, float& c, float& d) {
  float4 v = *(const float4*)p; a = v.x; b = v.y; c = v.z; d = v.w;
}
__device__ __forceinline__ void load4w(const unsigned short* p, float& a, float& b, float& c, float& d) {
  ushort4 v = *(const ushort4*)p; a = bf2f(v.x); b = bf2f(v.y); c = bf2f(v.z); d = bf2f(v.w);
}

// ---------------- adp = softmax(relu(nv1@nv2), axis=1) ----------------
__global__ __launch_bounds__(256) void adp_kernel(const float* __restrict__ nv1,
                                                  const float* __restrict__ nv2,
                                                  float* __restrict__ adp) {
  int i = blockIdx.x;           // row
  int j = threadIdx.x;          // 0..255, active < 144
  __shared__ float sm[256];
  float r = 0.f, v = -1e30f;
  if (j < 144) {
    for (int k = 0; k < 10; ++k) r += nv1[i * 10 + k] * nv2[k * 144 + j];
    r = fmaxf(r, 0.f);
    v = r;
  }
  sm[j] = v; __syncthreads();
  for (int s = 128; s > 0; s >>= 1) { if (j < s) sm[j] = fmaxf(sm[j], sm[j + s]); __syncthreads(); }
  float mx = sm[0]; __syncthreads();
  float e = (j < 144) ? expf(r - mx) : 0.f;
  sm[j] = e; __syncthreads();
  for (int s = 128; s > 0; s >>= 1) { if (j < s) sm[j] += sm[j + s]; __syncthreads(); }
  float sum = sm[0];
  if (j < 144) adp[i * 144 + j] = e / sum;
}

// ---------------- layer-0 effective input weights (K: 2304 -> 288) ----------------
__global__ __launch_bounds__(256)
void eff_weights(const float* __restrict__ WihF, const float* __restrict__ WihB,
                 const float* __restrict__ bihF, const float* __restrict__ bhhF,
                 const float* __restrict__ bihB, const float* __restrict__ bhhB,
                 const float* __restrict__ ws, const float* __restrict__ bs,
                 const float* __restrict__ wc, const float* __restrict__ bc,
                 float* __restrict__ Weff, float* __restrict__ beff) {
  const int r = blockIdx.x, dir = blockIdx.y;
  const float* W = dir ? WihB : WihF;
  __shared__ float red[256];
  const int n = threadIdx.x;
  float spb = 0.f;
  if (n < 144) {
    float sws = 0.f, swc = 0.f;
    #pragma unroll
    for (int c = 0; c < 16; ++c) {
      float w = W[(size_t)r * HN_ + c * 144 + n];
      sws += w * ws[c];
      swc += w * wc[c];
      spb += w * (bs[c] + bc[c]);
    }
    size_t base = ((size_t)dir * G4_ + r) * 288;
    Weff[base + n] = sws;
    Weff[base + 144 + n] = swc;
  }
  red[n] = spb; __syncthreads();
  for (int s = 128; s > 0; s >>= 1) { if (n < s) red[n] += red[n + s]; __syncthreads(); }
  if (n == 0) {
    const float* bih = dir ? bihB : bihF;
    const float* bhh = dir ? bhhB : bhhF;
    beff[dir * G4_ + r] = red[0] + bih[r] + bhh[r];
  }
}

// ---------------- build concatenated [inp|mask] A-matrix, rows m = t*8+b ----------------
__global__ void build_acat(const float* __restrict__ inpF, const float* __restrict__ mF,
                           const float* __restrict__ inpB, const float* __restrict__ mB,
                           float* __restrict__ Acat) {
  int idx = blockIdx.x * 256 + threadIdx.x;   // < 147456
  int dir = idx / 73728;
  int rem = idx - dir * 73728;
  int m = rem / 288;
  int n = rem - m * 288;
  int t = m >> 3, b = m & 7;
  const float* src;
  int nn = n;
  if (n < 144) src = dir ? inpB : inpF;
  else { src = dir ? mB : mF; nn = n - 144; }
  Acat[idx] = src[(size_t)(b * 32 + t) * 144 + nn];
}

// ---------------- generic fp32 GEMM: C[M,Nc] = A[M,K] * Bm[Nc,K]^T + biases ----------------
// grid: (Nc/64, M/32), block 256.  K % 16 == 0.
__global__ __launch_bounds__(256)
void gemm_bt(const float* __restrict__ A, const float* __restrict__ Bm,
             const float* __restrict__ bias1, const float* __restrict__ bias2,
             float* __restrict__ C, int M, int Nc, int K) {
  __shared__ float As[16 * 33];   // [k][r], r<32, padded
  __shared__ float Bs[16 * 65];   // [k][n], n<64, padded
  const int bm = blockIdx.y * 32, bn = blockIdx.x * 64;
  const int tx = threadIdx.x & 15;   // cols tx*4..+3
  const int ty = threadIdx.x >> 4;   // rows ty*2..+1
  float acc[2][4] = {};
  for (int k0 = 0; k0 < K; k0 += 16) {
    for (int i = threadIdx.x; i < 512; i += 256) {
      int r = i >> 4, c = i & 15;
      As[c * 33 + r] = A[(size_t)(bm + r) * K + k0 + c];
    }
    for (int i = threadIdx.x; i < 1024; i += 256) {
      int r = i >> 4, c = i & 15;
      Bs[c * 65 + r] = Bm[(size_t)(bn + r) * K + k0 + c];
    }
    __syncthreads();
    #pragma unroll
    for (int kk = 0; kk < 16; ++kk) {
      float a0 = As[kk * 33 + ty * 2], a1 = As[kk * 33 + ty * 2 + 1];
      float bv[4];
      #pragma unroll
      for (int q = 0; q < 4; ++q) bv[q] = Bs[kk * 65 + tx * 4 + q];
      #pragma unroll
      for (int q = 0; q < 4; ++q) { acc[0][q] += a0 * bv[q]; acc[1][q] += a1 * bv[q]; }
    }
    __syncthreads();
  }
  #pragma unroll
  for (int i = 0; i < 2; ++i) {
    int m = bm + ty * 2 + i;
    #pragma unroll
    for (int q = 0; q < 4; ++q) {
      int n = bn + tx * 4 + q;
      float v = acc[i][q];
      if (bias1) v += bias1[n];
      if (bias2) v += bias2[n];
      C[(size_t)m * Nc + n] = v;
    }
  }
}

// ---------------- fp32 -> bf16 weight convert ----------------
__global__ void cvt_bf16(const float* __restrict__ in, unsigned short* __restrict__ out, int n4) {
  int i = blockIdx.x * 256 + threadIdx.x;
  if (i >= n4) return;
  float4 v = ((const float4*)in)[i];
  ushort4 o;
  o.x = f2bf(v.x); o.y = f2bf(v.y); o.z = f2bf(v.z); o.w = f2bf(v.w);
  ((ushort4*)out)[i] = o;
}

// ---------------- one LSTM timestep: g = Gx[t] + h@Whh^T ; gate update ----------------
// grid (576, ndir), block 256 (4 waves). wave -> one cell j (4 gate rows x 8 batches).
template<typename WT>
__global__ __launch_bounds__(256)
void lstm_step(const WT* __restrict__ W0, const WT* __restrict__ W1,
               const float* __restrict__ Gx0, const float* __restrict__ Gx1,
               const float* __restrict__ hin0, const float* __restrict__ hin1,
               float* __restrict__ hout0, float* __restrict__ hout1,
               float* __restrict__ c0, float* __restrict__ c1,
               float* __restrict__ hs0, float* __restrict__ hs1,
               int t, int t_l) {
  const int dir = blockIdx.y;
  const WT* W = dir ? W1 : W0;
  const float* Gx = (dir ? Gx1 : Gx0) + (size_t)t * (8 * G4_);
  const float* hin = dir ? hin1 : hin0;
  float* hout = dir ? hout1 : hout0;
  float* cb = dir ? c1 : c0;
  float* hsout = dir ? hs1 : hs0;

  __shared__ float hsm[8 * 768];         // one-third of h at a time (24 KB)
  const int wave = threadIdx.x >> 6;
  const int lane = threadIdx.x & 63;
  const int j = blockIdx.x * 4 + wave;   // < 2304

  float acc[4][8];
  #pragma unroll
  for (int g = 0; g < 4; ++g)
    #pragma unroll
    for (int b = 0; b < 8; ++b) acc[g][b] = 0.f;

  const float4* hin4 = (const float4*)hin;
  float4* hsm4 = (float4*)hsm;

  for (int pass = 0; pass < 3; ++pass) {
    for (int i = threadIdx.x; i < 1536; i += 256) {
      int b = i / 192, q = i - b * 192;
      hsm4[b * 192 + q] = hin4[b * 576 + pass * 192 + q];
    }
    __syncthreads();
    #pragma unroll
    for (int ch = 0; ch < 3; ++ch) {
      const int kk = ch * 256 + lane * 4;
      const int kg = pass * 768 + kk;
      float hr[8][4];
      #pragma unroll
      for (int b = 0; b < 8; ++b) {
        float4 hv = *(const float4*)&hsm[b * 768 + kk];
        hr[b][0] = hv.x; hr[b][1] = hv.y; hr[b][2] = hv.z; hr[b][3] = hv.w;
      }
      #pragma unroll
      for (int g = 0; g < 4; ++g) {
        float w0, w1, w2, w3;
        load4w(W + (size_t)(g * HN_ + j) * HN_ + kg, w0, w1, w2, w3);
        #pragma unroll
        for (int b = 0; b < 8; ++b)
          acc[g][b] += w0 * hr[b][0] + w1 * hr[b][1] + w2 * hr[b][2] + w3 * hr[b][3];
      }
    }
    __syncthreads();
  }
  // butterfly-reduce each (gate,batch) across the 64 lanes
  #pragma unroll
  for (int g = 0; g < 4; ++g)
    #pragma unroll
    for (int b = 0; b < 8; ++b)
      #pragma unroll
      for (int m = 1; m < 64; m <<= 1)
        acc[g][b] += __shfl_xor(acc[g][b], m, 64);

  if (lane < 8) {
    const int b = lane;
    float d[4];
    #pragma unroll
    for (int g = 0; g < 4; ++g) {
      float v = acc[g][0];
      #pragma unroll
      for (int bb = 1; bb < 8; ++bb) v = (b == bb) ? acc[g][bb] : v;
      d[g] = v;
    }
    const float gi = Gx[b * G4_ + 0 * HN_ + j] + d[0];
    const float gf = Gx[b * G4_ + 1 * HN_ + j] + d[1];
    const float gg = Gx[b * G4_ + 2 * HN_ + j] + d[2];
    const float go = Gx[b * G4_ + 3 * HN_ + j] + d[3];
    const float si = 1.f / (1.f + expf(-gi));
    const float sf = 1.f / (1.f + expf(-gf));
    const float so = 1.f / (1.f + expf(-go));
    const float cn = sf * cb[b * HN_ + j] + si * tanhf(gg);
    const float hv = so * tanhf(cn);
    cb[b * HN_ + j] = cn;
    hout[b * HN_ + j] = hv;
    hsout[(size_t)(b * HN_ + j) * t_l + t] = hv;
  }
}

// ---------------- (hs_fw + reverse(hs_bw))/2 -> tanh (or tanh only) ----------------
__global__ void combine_tanh(const float* __restrict__ hsF, const float* __restrict__ hsB,
                             float* __restrict__ gin, int t_l, int total) {
  int idx = blockIdx.x * 256 + threadIdx.x;
  if (idx >= total) return;
  int t = idx % t_l;
  float v;
  if (hsB) v = 0.5f * (hsF[idx] + hsB[idx - t + (t_l - 1 - t)]);
  else v = hsF[idx];
  gin[idx] = tanhf(v);
}

// ---------------- graph diffusion: out[.,w,t] = sum_v in[.,v,t] * A[v,w] ----------------
__global__ void gc1(const float* __restrict__ in, const float* __restrict__ A,
                    float* __restrict__ out, int t_l, int total) {
  int idx = blockIdx.x * 256 + threadIdx.x;
  if (idx >= total) return;
  int t = idx % t_l;
  int w = (idx / t_l) % 144;
  int bc = idx / (t_l * 144);
  const float* src = in + (size_t)bc * 144 * t_l + t;
  float acc = 0.f;
  for (int v = 0; v < 144; ++v) acc += src[(size_t)v * t_l] * A[v * 144 + w];
  out[idx] = acc;
}

// ---------------- 1x1 conv over concat(x,x1,x2) + residual accumulate ----------------
__global__ void gc_out(const float* __restrict__ g0, const float* __restrict__ g1,
                       const float* __restrict__ g2, const float* __restrict__ Wg,
                       const float* __restrict__ bg, const float* __restrict__ prev,
                       float* __restrict__ out, int t_l, int total) {
  int idx = blockIdx.x * 256 + threadIdx.x;
  if (idx >= total) return;
  int t = idx % t_l;
  int n = (idx / t_l) % 144;
  int o = (idx / (t_l * 144)) % 16;
  int b = idx / (t_l * 144 * 16);
  float acc = bg[o];
  size_t base = ((size_t)b * 16 * 144 + n) * t_l + t;
  #pragma unroll
  for (int c = 0; c < 16; ++c) {
    size_t s = base + (size_t)c * 144 * t_l;
    acc += Wg[o * 48 + c] * g0[s] + Wg[o * 48 + 16 + c] * g1[s] + Wg[o * 48 + 32 + c] * g2[s];
  }
  if (prev) acc += prev[((size_t)(b * 16 + o) * 144 + n) * 32 + 16 + t];
  out[idx] = acc;
}

// ---------------- batchnorm (training stats) over go[...,::2]; writes xT for next GEMM ----------------
__global__ __launch_bounds__(256)
void bn_xt(const float* __restrict__ go, const float* __restrict__ gamma,
           const float* __restrict__ beta, float* __restrict__ xT) {
  int c = blockIdx.x;    // channel
  __shared__ float s1[256], s2[256];
  float sum = 0.f, sq = 0.f;
  for (int i = threadIdx.x; i < 18432; i += 256) {
    int b = i / 2304; int rem = i - b * 2304; int n = rem / 16; int tt = rem & 15;
    float v = go[((size_t)(b * 16 + c) * 144 + n) * 32 + 2 * tt];
    sum += v; sq += v * v;
  }
  s1[threadIdx.x] = sum; s2[threadIdx.x] = sq; __syncthreads();
  for (int s = 128; s > 0; s >>= 1) {
    if (threadIdx.x < s) { s1[threadIdx.x] += s1[threadIdx.x + s]; s2[threadIdx.x] += s2[threadIdx.x + s]; }
    __syncthreads();
  }
  float mean = s1[0] / 18432.f;
  float var = s2[0] / 18432.f - mean * mean;
  float rs = rsqrtf(var + 1e-5f);
  float scale = gamma[c] * rs, shift = beta[c] - mean * scale;
  for (int i = threadIdx.x; i < 18432; i += 256) {
    int b = i / 2304; int rem = i - b * 2304; int n = rem / 16; int tt = rem & 15;
    float v = go[((size_t)(b * 16 + c) * 144 + n) * 32 + 2 * tt];
    xT[(size_t)(tt * 8 + b) * HN_ + c * 144 + n] = v * scale + shift;
  }
}

// ---------------- epilogue chain ----------------
__global__ void e1_kernel(const float* __restrict__ in, const float* __restrict__ W,
                          const float* __restrict__ bias, float* __restrict__ out) {
  int idx = blockIdx.x * 256 + threadIdx.x;   // 294912
  int tt = idx & 15;
  int n = (idx >> 4) % 144;
  int o = (idx / (16 * 144)) % 16;
  int b = idx / (16 * 144 * 16);
  float acc = bias[o];
  size_t base = ((size_t)b * 16 * 144 + n) * 16 + tt;
  #pragma unroll
  for (int c = 0; c < 16; ++c) acc += in[base + (size_t)c * 144 * 16] * W[o * 16 + c];
  out[idx] = acc;
}
__global__ void e2_kernel(const float* __restrict__ in, const float* __restrict__ W,
                          const float* __restrict__ bias, float* __restrict__ out) {
  int idx = blockIdx.x * 256 + threadIdx.x;   // 589824
  int tt = idx & 15;
  int n = (idx >> 4) % 144;
  int o2 = (idx / (16 * 144)) % 32;
  int b = idx / (16 * 144 * 32);
  float acc = bias[o2];
  size_t base = ((size_t)b * 16 * 144 + n) * 16 + tt;
  #pragma unroll
  for (int o = 0; o < 16; ++o) acc += in[base + (size_t)o * 144 * 16] * W[o2 * 16 + o];
  out[idx] = acc;
}
__global__ void e3_kernel(const float* __restrict__ in, const float* __restrict__ Wlo,
                          const float* __restrict__ blo, float* __restrict__ out) {
  int idx = blockIdx.x * 256 + threadIdx.x;   // 36864
  int n = idx % 144;
  int o2 = (idx / 144) % 32;
  int b = idx / (144 * 32);
  float acc = blo[0];
  size_t base = ((size_t)(b * 32 + o2) * 144 + n) * 16;
  #pragma unroll
  for (int tt = 0; tt < 16; ++tt) acc += in[base + tt] * Wlo[tt];
  out[idx] = acc;
}
__global__ void f1_kernel(const float* __restrict__ o3, const float* __restrict__ y,
                          const float* __restrict__ ym, const float* __restrict__ W,
                          const float* __restrict__ bias, float* __restrict__ out) {
  int idx = blockIdx.x * 256 + threadIdx.x;   // 32768
  int k = idx & 127;
  int t = (idx >> 7) & 31;
  int b = idx >> 12;
  float acc = bias[k];
  size_t rb = (size_t)(b * 32 + t) * 144;
  const float* wr = W + k * 432;
  for (int n = 0; n < 144; ++n)
    acc += o3[rb + n] * wr[n] + y[rb + n] * wr[144 + n] + ym[rb + n] * wr[288 + n];
  out[idx] = acc;
}
__global__ void f2_kernel(const float* __restrict__ f1b, const float* __restrict__ W,
                          const float* __restrict__ bias, float* __restrict__ out) {
  int idx = blockIdx.x * 256 + threadIdx.x;   // 36864
  int n = idx % 144;
  int t = (idx / 144) % 32;
  int b = idx / (144 * 32);
  float acc = bias[n];
  size_t fb = (size_t)(b * 32 + t) * 128;
  const float* wr = W + n * 128;
  #pragma unroll 4
  for (int k = 0; k < 128; ++k) acc += f1b[fb + k] * wr[k];
  out[idx] = acc;
}

extern "C" void kernel_launch(void* const* d_in, const int* in_sizes, int n_in,
                              void* d_out, int out_size, void* d_ws, size_t ws_size,
                              hipStream_t stream) {
  const float* input_tensor = (const float*)d_in[0];
  const float* mask_    = (const float*)d_in[1];
  const float* input_bw = (const float*)d_in[2];
  const float* mask_bw  = (const float*)d_in[3];
  const float* y_in     = (const float*)d_in[4];
  const float* ymask    = (const float*)d_in[5];
  const float* ws_p = (const float*)d_in[6];
  const float* bs_p = (const float*)d_in[7];
  const float* wc_p = (const float*)d_in[8];
  const float* bc_p = (const float*)d_in[9];
  const float* nv1 = (const float*)d_in[10];
  const float* nv2 = (const float*)d_in[11];
  const float* Wih_fw = (const float*)d_in[12];
  const float* Whh_fw = (const float*)d_in[13];
  const float* bih_fw = (const float*)d_in[14];
  const float* bhh_fw = (const float*)d_in[15];
  const float* Wih_bw = (const float*)d_in[16];
  const float* Whh_bw = (const float*)d_in[17];
  const float* bih_bw = (const float*)d_in[18];
  const float* bhh_bw = (const float*)d_in[19];
  const float* Wg   = (const float*)d_in[20];
  const float* bg   = (const float*)d_in[21];
  const float* gam  = (const float*)d_in[22];
  const float* bet  = (const float*)d_in[23];
  const float* W_end1 = (const float*)d_in[24];
  const float* b_end1 = (const float*)d_in[25];
  const float* W_end2 = (const float*)d_in[26];
  const float* b_end2 = (const float*)d_in[27];
  const float* W_lo = (const float*)d_in[28];
  const float* b_lo = (const float*)d_in[29];
  const float* W_f1 = (const float*)d_in[30];
  const float* b_f1 = (const float*)d_in[31];
  const float* W_f2 = (const float*)d_in[32];
  const float* b_f2 = (const float*)d_in[33];

  char* base = (char*)d_ws;
  size_t off = 0;
  auto alloc = [&](size_t bytes) -> char* {
    char* p = base + off;
    off += (bytes + 255) & ~(size_t)255;
    return p;
  };
  float* adp  = (float*)alloc(144 * 144 * 4);
  float* Weff = (float*)alloc((size_t)2 * G4_ * 288 * 4);
  float* beff = (float*)alloc(2 * G4_ * 4);
  float* Acat = (float*)alloc((size_t)2 * 256 * 288 * 4);
  float* GxF  = (float*)alloc((size_t)256 * G4_ * 4);
  float* GxB  = (float*)alloc((size_t)256 * G4_ * 4);
  float* hc   = (float*)alloc((size_t)9 * 18432 * 4);
  float* hsF  = (float*)alloc((size_t)589824 * 4);
  float* hsB  = (float*)alloc((size_t)589824 * 4);
  float* hsL  = (float*)alloc((size_t)294912 * 4);
  float* gin  = (float*)alloc((size_t)589824 * 4);
  float* x1b  = (float*)alloc((size_t)589824 * 4);
  float* x2b  = (float*)alloc((size_t)589824 * 4);
  float* out0 = (float*)alloc((size_t)589824 * 4);
  float* out1 = (float*)alloc((size_t)294912 * 4);
  float* xT   = (float*)alloc((size_t)294912 * 4);
  float* tmp1 = (float*)alloc((size_t)294912 * 4);
  float* tmp2 = (float*)alloc((size_t)589824 * 4);
  float* out3 = (float*)alloc((size_t)36864 * 4);
  float* f1b  = (float*)alloc((size_t)32768 * 4);
  unsigned short* Wh16a = (unsigned short*)alloc((size_t)G4_ * HN_ * 2);
  unsigned short* Wh16b = (unsigned short*)alloc((size_t)G4_ * HN_ * 2);
  const bool use_bf16 = (off <= ws_size);

  float* h0F = hc, *h1F = hc + 18432, *cF = hc + 2 * 18432;
  float* h0B = hc + 3 * 18432, *h1B = hc + 4 * 18432, *cB = hc + 5 * 18432;
  float* h0L = hc + 6 * 18432, *h1L = hc + 7 * 18432, *cL = hc + 8 * 18432;

  hipMemsetAsync(hc, 0, (size_t)9 * 18432 * 4, stream);

  adp_kernel<<<144, 256, 0, stream>>>(nv1, nv2, adp);
  eff_weights<<<dim3(G4_, 2), 256, 0, stream>>>(Wih_fw, Wih_bw, bih_fw, bhh_fw, bih_bw, bhh_bw,
                                                ws_p, bs_p, wc_p, bc_p, Weff, beff);
  build_acat<<<576, 256, 0, stream>>>(input_tensor, mask_, input_bw, mask_bw, Acat);
  gemm_bt<<<dim3(144, 8), 256, 0, stream>>>(Acat, Weff, beff, nullptr, GxF, 256, G4_, 288);
  gemm_bt<<<dim3(144, 8), 256, 0, stream>>>(Acat + (size_t)256 * 288, Weff + (size_t)G4_ * 288,
                                            beff + G4_, nullptr, GxB, 256, G4_, 288);
  const int n4 = (G4_ * HN_) / 4;   // 5308416
  if (use_bf16) {
    cvt_bf16<<<n4 / 256, 256, 0, stream>>>(Whh_fw, Wh16a, n4);
    cvt_bf16<<<n4 / 256, 256, 0, stream>>>(Whh_bw, Wh16b, n4);
  }

  // ---- layer-0 scan (fw + bw concurrently) ----
  for (int t = 0; t < 32; ++t) {
    float* hiF = (t & 1) ? h1F : h0F; float* hoF = (t & 1) ? h0F : h1F;
    float* hiB = (t & 1) ? h1B : h0B; float* hoB = (t & 1) ? h0B : h1B;
    if (use_bf16)
      lstm_step<unsigned short><<<dim3(576, 2), 256, 0, stream>>>(
          Wh16a, Wh16b, GxF, GxB, hiF, hiB, hoF, hoB, cF, cB, hsF, hsB, t, 32);
    else
      lstm_step<float><<<dim3(576, 2), 256, 0, stream>>>(
          Whh_fw, Whh_bw, GxF, GxB, hiF, hiB, hoF, hoB, cF, cB, hsF, hsB, t, 32);
  }

  combine_tanh<<<2304, 256, 0, stream>>>(hsF, hsB, gin, 32, 589824);
  gc1<<<2304, 256, 0, stream>>>(gin, adp, x1b, 32, 589824);
  gc1<<<2304, 256, 0, stream>>>(x1b, adp, x2b, 32, 589824);
  gc_out<<<2304, 256, 0, stream>>>(gin, x1b, x2b, Wg, bg, nullptr, out0, 32, 589824);
  bn_xt<<<16, 256, 0, stream>>>(out0, gam, bet, xT);

  const size_t WL1_off = (size_t)G4_ * HN_;
  gemm_bt<<<dim3(144, 4), 256, 0, stream>>>(xT, Wih_fw + WL1_off, bih_fw + G4_, bhh_fw + G4_,
                                            GxF, 128, G4_, 2304);
  if (use_bf16)
    cvt_bf16<<<n4 / 256, 256, 0, stream>>>(Whh_fw + WL1_off, Wh16a, n4);

  // ---- layer-1 scan ----
  for (int t = 0; t < 16; ++t) {
    float* hi = (t & 1) ? h1L : h0L; float* ho = (t & 1) ? h0L : h1L;
    if (use_bf16)
      lstm_step<unsigned short><<<dim3(576, 1), 256, 0, stream>>>(
          Wh16a, Wh16a, GxF, GxF, hi, hi, ho, ho, cL, cL, hsL, hsL, t, 16);
    else
      lstm_step<float><<<dim3(576, 1), 256, 0, stream>>>(
          Whh_fw + WL1_off, Whh_fw + WL1_off, GxF, GxF, hi, hi, ho, ho, cL, cL, hsL, hsL, t, 16);
  }

  combine_tanh<<<1152, 256, 0, stream>>>(hsL, nullptr, gin, 16, 294912);
  gc1<<<1152, 256, 0, stream>>>(gin, adp, x1b, 16, 294912);
  gc1<<<1152, 256, 0, stream>>>(x1b, adp, x2b, 16, 294912);
  gc_out<<<1152, 256, 0, stream>>>(gin, x1b, x2b, Wg + 16 * 48, bg + 16, out0, out1, 16, 294912);

  e1_kernel<<<1152, 256, 0, stream>>>(out1, W_end1, b_end1, tmp1);
  e2_kernel<<<2304, 256, 0, stream>>>(tmp1, W_end2, b_end2, tmp2);
  e3_kernel<<<144, 256, 0, stream>>>(tmp2, W_lo, b_lo, out3);
  f1_kernel<<<128, 256, 0, stream>>>(out3, y_in, ymask, W_f1, b_f1, f1b);
  f2_kernel<<<144, 256, 0, stream>>>(f1b, W_f2, b_f2, (float*)d_out);
}

// Round 2
// 1738.633 us; speedup vs baseline: 1.4698x; 1.4698x over previous
//
#include <hip/hip_runtime.h>
#include <cstdint>
#include <cstddef>

#define HN_ 2304
#define G4_ 9216

typedef __attribute__((ext_vector_type(8))) short v8s;
typedef __attribute__((ext_vector_type(4))) float v4f;

__device__ __forceinline__ unsigned short f2bf(float x) {
  union { float f; unsigned int i; } v; v.f = x;
  unsigned int r = (v.i + 0x7fffu + ((v.i >> 16) & 1u)) >> 16;
  return (unsigned short)r;
}

// ---------------- adp = softmax(relu(nv1@nv2), axis=1) ----------------
__global__ __launch_bounds__(256) void adp_kernel(const float* __restrict__ nv1,
                                                  const float* __restrict__ nv2,
                                                  float* __restrict__ adp) {
  int i = blockIdx.x;
  int j = threadIdx.x;
  __shared__ float sm[256];
  float r = 0.f, v = -1e30f;
  if (j < 144) {
    for (int k = 0; k < 10; ++k) r += nv1[i * 10 + k] * nv2[k * 144 + j];
    r = fmaxf(r, 0.f);
    v = r;
  }
  sm[j] = v; __syncthreads();
  for (int s = 128; s > 0; s >>= 1) { if (j < s) sm[j] = fmaxf(sm[j], sm[j + s]); __syncthreads(); }
  float mx = sm[0]; __syncthreads();
  float e = (j < 144) ? expf(r - mx) : 0.f;
  sm[j] = e; __syncthreads();
  for (int s = 128; s > 0; s >>= 1) { if (j < s) sm[j] += sm[j + s]; __syncthreads(); }
  float sum = sm[0];
  if (j < 144) adp[i * 144 + j] = e / sum;
}

// ---------------- layer-0 effective input weights, written as packed bf16 frags ----------------
// Packed layout (per dir): frag pos = ((nt*9 + ks)*64 + lane)*8 + e, lane = ((k>>3)&3)*16 + col,
// col = jj*4 + g, r = g*2304 + nt*4 + jj.
__global__ __launch_bounds__(256)
void eff_weights(const float* __restrict__ WihF, const float* __restrict__ WihB,
                 const float* __restrict__ bihF, const float* __restrict__ bhhF,
                 const float* __restrict__ bihB, const float* __restrict__ bhhB,
                 const float* __restrict__ ws, const float* __restrict__ bs,
                 const float* __restrict__ wc, const float* __restrict__ bc,
                 unsigned short* __restrict__ Wpk, float* __restrict__ beff) {
  const int r = blockIdx.x, dir = blockIdx.y;
  const float* W = dir ? WihB : WihF;
  __shared__ float red[256];
  const int n = threadIdx.x;
  float spb = 0.f;
  if (n < 144) {
    float sws = 0.f, swc = 0.f;
    #pragma unroll
    for (int c = 0; c < 16; ++c) {
      float w = W[(size_t)r * HN_ + c * 144 + n];
      sws += w * ws[c];
      swc += w * wc[c];
      spb += w * (bs[c] + bc[c]);
    }
    const int rm = r % 2304;
    const int g = r / 2304;
    const int nt = rm >> 2, col = (rm & 3) * 4 + g;
    unsigned short* outp = Wpk + (size_t)dir * 2654208;
    int k = n;
    outp[((size_t)(nt * 9 + (k >> 5)) * 64 + ((k >> 3) & 3) * 16 + col) * 8 + (k & 7)] = f2bf(sws);
    k = 144 + n;
    outp[((size_t)(nt * 9 + (k >> 5)) * 64 + ((k >> 3) & 3) * 16 + col) * 8 + (k & 7)] = f2bf(swc);
  }
  red[n] = spb; __syncthreads();
  for (int s = 128; s > 0; s >>= 1) { if (n < s) red[n] += red[n + s]; __syncthreads(); }
  if (n == 0) {
    const float* bih = dir ? bihB : bihF;
    const float* bhh = dir ? bhhB : bhhF;
    beff[dir * G4_ + r] = red[0] + bih[r] + bhh[r];
  }
}

// ---------------- build A fragments for layer-0 input GEMM (bf16) ----------------
// A[m][k]: m = t*8+b (M=256), k in [0,288): k<144 -> input[b][t][k], else mask[b][t][k-144]
__global__ void build_acat_frag(const float* __restrict__ inF, const float* __restrict__ mF,
                                const float* __restrict__ inB, const float* __restrict__ mB,
                                unsigned short* __restrict__ out) {
  int idx = blockIdx.x * 256 + threadIdx.x;   // 18432 frags total
  int lane = idx & 63;
  int ks = (idx >> 6) % 9;
  int mt = (idx / (64 * 9)) % 16;
  int dir = idx / (64 * 9 * 16);
  int m = mt * 16 + (lane & 15);
  int k = ks * 32 + (lane >> 4) * 8;
  int t = m >> 3, b = m & 7;
  const float* src; int kk = k;
  if (k < 144) src = dir ? inB : inF;
  else { src = dir ? mB : mF; kk = k - 144; }
  const float* p = src + ((size_t)b * 32 + t) * 144 + kk;
  v8s o;
  #pragma unroll
  for (int e = 0; e < 8; ++e) o[e] = (short)f2bf(p[e]);
  ((v8s*)out)[idx] = o;
}

// ---------------- pack a [9216 x 2304] weight matrix into gate-interleaved bf16 frags ----------------
__global__ void pack_whh(const float* __restrict__ W, unsigned short* __restrict__ out) {
  int idx = blockIdx.x * 256 + threadIdx.x;   // 576*72*64 = 2,654,208
  int lane = idx & 63;
  int ks = (idx >> 6) % 72;
  int nt = idx / (64 * 72);
  int col = lane & 15, q = lane >> 4;
  int r = (col & 3) * 2304 + nt * 4 + (col >> 2);
  int k = ks * 32 + q * 8;
  const float* src = W + (size_t)r * 2304 + k;
  float4 v0 = *(const float4*)src;
  float4 v1 = *(const float4*)(src + 4);
  v8s o;
  o[0] = (short)f2bf(v0.x); o[1] = (short)f2bf(v0.y);
  o[2] = (short)f2bf(v0.z); o[3] = (short)f2bf(v0.w);
  o[4] = (short)f2bf(v1.x); o[5] = (short)f2bf(v1.y);
  o[6] = (short)f2bf(v1.z); o[7] = (short)f2bf(v1.w);
  ((v8s*)out)[idx] = o;
}

// ---------------- MFMA GEMM over fragment-packed operands; writes Gx[t][nt][col][b] ----------------
// grid (576, Mtiles/4), block 64. Apk: [mt][nks][64][8] bf16. Wpk: [nt][nks][64][8] bf16.
__global__ __launch_bounds__(64)
void gemm_frag(const unsigned short* __restrict__ Apk, const unsigned short* __restrict__ Wpk,
               const float* __restrict__ b1, const float* __restrict__ b2,
               float* __restrict__ Gx, int nks) {
  const int lane = threadIdx.x;
  const int nt = blockIdx.x;
  const int mtb = blockIdx.y * 4;
  v4f acc[4] = {};
  const v8s* Bp = (const v8s*)Wpk + (size_t)nt * nks * 64;
  const v8s* Ap = (const v8s*)Apk;
  for (int ks = 0; ks < nks; ++ks) {
    v8s bf = Bp[ks * 64 + lane];
    #pragma unroll
    for (int mi = 0; mi < 4; ++mi) {
      v8s af = Ap[(size_t)((mtb + mi) * nks + ks) * 64 + lane];
      acc[mi] = __builtin_amdgcn_mfma_f32_16x16x32_bf16(af, bf, acc[mi], 0, 0, 0);
    }
  }
  const int col = lane & 15;
  const int jj = col >> 2, g = col & 3;
  const int rw = g * 2304 + nt * 4 + jj;
  float bsum = b1[rw] + (b2 ? b2[rw] : 0.f);
  #pragma unroll
  for (int mi = 0; mi < 4; ++mi)
    #pragma unroll
    for (int r = 0; r < 4; ++r) {
      int m = (mtb + mi) * 16 + (lane >> 4) * 4 + r;
      int t = m >> 3, b = m & 7;
      Gx[((size_t)t * 576 + nt) * 128 + col * 8 + b] = acc[mi][r] + bsum;
    }
}

// ---------------- one LSTM timestep via MFMA ----------------
// grid (144, ndir), block 256 (4 waves, wave -> ntile). A = h (bf16 frag-linear), B = packed Whh.
__global__ __launch_bounds__(256)
void lstm_mfma(const unsigned short* __restrict__ Wpk0, const unsigned short* __restrict__ Wpk1,
               const float* __restrict__ Gx0, const float* __restrict__ Gx1,
               const unsigned short* __restrict__ hin0, const unsigned short* __restrict__ hin1,
               unsigned short* __restrict__ hout0, unsigned short* __restrict__ hout1,
               float* __restrict__ c0, float* __restrict__ c1,
               float* __restrict__ hs0, float* __restrict__ hs1,
               int t, int t_l) {
  const int dir = blockIdx.y;
  const unsigned short* Wpk = dir ? Wpk1 : Wpk0;
  const float* Gx = (dir ? Gx1 : Gx0) + (size_t)t * 73728;
  const unsigned short* hin = dir ? hin1 : hin0;
  unsigned short* hout = dir ? hout1 : hout0;
  float* cb = dir ? c1 : c0;
  float* hsout = dir ? hs1 : hs0;

  __shared__ unsigned short Ash[36864];  // 72 ks * 64 lanes * 8 bf16 = 73728 B
  for (int i = threadIdx.x; i < 4608; i += 256)
    ((float4*)Ash)[i] = ((const float4*)hin)[i];
  __syncthreads();

  const int lane = threadIdx.x & 63;
  const int wave = threadIdx.x >> 6;
  const int nt = blockIdx.x * 4 + wave;   // 0..575

  v4f acc = {0.f, 0.f, 0.f, 0.f};
  const v8s* Ap = (const v8s*)Ash;
  const v8s* Bp = (const v8s*)Wpk + (size_t)nt * 72 * 64;
  #pragma unroll 8
  for (int ks = 0; ks < 72; ++ks) {
    v8s af = Ap[ks * 64 + lane];
    v8s bf = Bp[ks * 64 + lane];
    acc = __builtin_amdgcn_mfma_f32_16x16x32_bf16(af, bf, acc, 0, 0, 0);
  }

  // D: col=lane&15 (jj*4+g), row=(lane>>4)*4+r (batch; rows 0-7 valid)
  float vI[4], vF[4], vG[4], vO[4];
  #pragma unroll
  for (int r = 0; r < 4; ++r) {
    float a = acc[r];
    vI[r] = a;
    vF[r] = __shfl_xor(a, 1, 64);
    vG[r] = __shfl_xor(a, 2, 64);
    vO[r] = __shfl_xor(a, 3, 64);
  }
  const int col = lane & 15;
  if ((lane & 3) == 0 && lane < 32) {
    const int j = nt * 4 + (col >> 2);
    #pragma unroll
    for (int r = 0; r < 4; ++r) {
      const int b = (lane >> 4) * 4 + r;
      const float gi = vI[r] + Gx[(nt * 16 + col + 0) * 8 + b];
      const float gf = vF[r] + Gx[(nt * 16 + col + 1) * 8 + b];
      const float gg = vG[r] + Gx[(nt * 16 + col + 2) * 8 + b];
      const float go = vO[r] + Gx[(nt * 16 + col + 3) * 8 + b];
      const float si = 1.f / (1.f + expf(-gi));
      const float sf = 1.f / (1.f + expf(-gf));
      const float so = 1.f / (1.f + expf(-go));
      const float cn = sf * cb[b * HN_ + j] + si * tanhf(gg);
      const float hv = so * tanhf(cn);
      cb[b * HN_ + j] = cn;
      hsout[(size_t)(b * HN_ + j) * t_l + t] = hv;
      hout[((size_t)(j >> 5) * 64 + ((j >> 3) & 3) * 16 + b) * 8 + (j & 7)] = f2bf(hv);
    }
  }
}

// ---------------- (hs_fw + reverse(hs_bw))/2 -> tanh (or tanh only) ----------------
__global__ void combine_tanh(const float* __restrict__ hsF, const float* __restrict__ hsB,
                             float* __restrict__ gin, int t_l, int total) {
  int idx = blockIdx.x * 256 + threadIdx.x;
  if (idx >= total) return;
  int t = idx % t_l;
  float v;
  if (hsB) v = 0.5f * (hsF[idx] + hsB[idx - t + (t_l - 1 - t)]);
  else v = hsF[idx];
  gin[idx] = tanhf(v);
}

// ---------------- graph diffusion ----------------
__global__ void gc1(const float* __restrict__ in, const float* __restrict__ A,
                    float* __restrict__ out, int t_l, int total) {
  int idx = blockIdx.x * 256 + threadIdx.x;
  if (idx >= total) return;
  int t = idx % t_l;
  int w = (idx / t_l) % 144;
  int bc = idx / (t_l * 144);
  const float* src = in + (size_t)bc * 144 * t_l + t;
  float acc = 0.f;
  for (int v = 0; v < 144; ++v) acc += src[(size_t)v * t_l] * A[v * 144 + w];
  out[idx] = acc;
}

// ---------------- 1x1 conv over concat(x,x1,x2) + residual accumulate ----------------
__global__ void gc_out(const float* __restrict__ g0, const float* __restrict__ g1,
                       const float* __restrict__ g2, const float* __restrict__ Wg,
                       const float* __restrict__ bg, const float* __restrict__ prev,
                       float* __restrict__ out, int t_l, int total) {
  int idx = blockIdx.x * 256 + threadIdx.x;
  if (idx >= total) return;
  int t = idx % t_l;
  int n = (idx / t_l) % 144;
  int o = (idx / (t_l * 144)) % 16;
  int b = idx / (t_l * 144 * 16);
  float acc = bg[o];
  size_t base = ((size_t)b * 16 * 144 + n) * t_l + t;
  #pragma unroll
  for (int c = 0; c < 16; ++c) {
    size_t s = base + (size_t)c * 144 * t_l;
    acc += Wg[o * 48 + c] * g0[s] + Wg[o * 48 + 16 + c] * g1[s] + Wg[o * 48 + 32 + c] * g2[s];
  }
  if (prev) acc += prev[((size_t)(b * 16 + o) * 144 + n) * 32 + 16 + t];
  out[idx] = acc;
}

// ---------------- batchnorm over go[...,::2]; writes bf16 A-fragments for layer-1 GEMM ----------------
__global__ __launch_bounds__(256)
void bn_xt(const float* __restrict__ go, const float* __restrict__ gamma,
           const float* __restrict__ beta, unsigned short* __restrict__ xbf) {
  int c = blockIdx.x;    // channel
  __shared__ float s1[256], s2[256];
  float sum = 0.f, sq = 0.f;
  for (int i = threadIdx.x; i < 18432; i += 256) {
    int b = i / 2304; int rem = i - b * 2304; int n = rem / 16; int tt = rem & 15;
    float v = go[((size_t)(b * 16 + c) * 144 + n) * 32 + 2 * tt];
    sum += v; sq += v * v;
  }
  s1[threadIdx.x] = sum; s2[threadIdx.x] = sq; __syncthreads();
  for (int s = 128; s > 0; s >>= 1) {
    if (threadIdx.x < s) { s1[threadIdx.x] += s1[threadIdx.x + s]; s2[threadIdx.x] += s2[threadIdx.x + s]; }
    __syncthreads();
  }
  float mean = s1[0] / 18432.f;
  float var = s2[0] / 18432.f - mean * mean;
  float rs = rsqrtf(var + 1e-5f);
  float scale = gamma[c] * rs, shift = beta[c] - mean * scale;
  for (int i = threadIdx.x; i < 18432; i += 256) {
    int b = i / 2304; int rem = i - b * 2304; int n = rem / 16; int tt = rem & 15;
    float v = go[((size_t)(b * 16 + c) * 144 + n) * 32 + 2 * tt];
    int m = tt * 8 + b;
    int k = c * 144 + n;
    size_t pos = ((size_t)((m >> 4) * 72 + (k >> 5)) * 64 + ((k >> 3) & 3) * 16 + (m & 15)) * 8 + (k & 7);
    xbf[pos] = f2bf(v * scale + shift);
  }
}

// ---------------- epilogue chain ----------------
__global__ void e1_kernel(const float* __restrict__ in, const float* __restrict__ W,
                          const float* __restrict__ bias, float* __restrict__ out) {
  int idx = blockIdx.x * 256 + threadIdx.x;   // 294912
  int tt = idx & 15;
  int n = (idx >> 4) % 144;
  int o = (idx / (16 * 144)) % 16;
  int b = idx / (16 * 144 * 16);
  float acc = bias[o];
  size_t base = ((size_t)b * 16 * 144 + n) * 16 + tt;
  #pragma unroll
  for (int c = 0; c < 16; ++c) acc += in[base + (size_t)c * 144 * 16] * W[o * 16 + c];
  out[idx] = acc;
}
__global__ void e2_kernel(const float* __restrict__ in, const float* __restrict__ W,
                          const float* __restrict__ bias, float* __restrict__ out) {
  int idx = blockIdx.x * 256 + threadIdx.x;   // 589824
  int tt = idx & 15;
  int n = (idx >> 4) % 144;
  int o2 = (idx / (16 * 144)) % 32;
  int b = idx / (16 * 144 * 32);
  float acc = bias[o2];
  size_t base = ((size_t)b * 16 * 144 + n) * 16 + tt;
  #pragma unroll
  for (int o = 0; o < 16; ++o) acc += in[base + (size_t)o * 144 * 16] * W[o2 * 16 + o];
  out[idx] = acc;
}
__global__ void e3_kernel(const float* __restrict__ in, const float* __restrict__ Wlo,
                          const float* __restrict__ blo, float* __restrict__ out) {
  int idx = blockIdx.x * 256 + threadIdx.x;   // 36864
  int n = idx % 144;
  int o2 = (idx / 144) % 32;
  int b = idx / (144 * 32);
  float acc = blo[0];
  size_t base = ((size_t)(b * 32 + o2) * 144 + n) * 16;
  #pragma unroll
  for (int tt = 0; tt < 16; ++tt) acc += in[base + tt] * Wlo[tt];
  out[idx] = acc;
}
__global__ void f1_kernel(const float* __restrict__ o3, const float* __restrict__ y,
                          const float* __restrict__ ym, const float* __restrict__ W,
                          const float* __restrict__ bias, float* __restrict__ out) {
  int idx = blockIdx.x * 256 + threadIdx.x;   // 32768
  int k = idx & 127;
  int t = (idx >> 7) & 31;
  int b = idx >> 12;
  float acc = bias[k];
  size_t rb = (size_t)(b * 32 + t) * 144;
  const float* wr = W + k * 432;
  for (int n = 0; n < 144; ++n)
    acc += o3[rb + n] * wr[n] + y[rb + n] * wr[144 + n] + ym[rb + n] * wr[288 + n];
  out[idx] = acc;
}
__global__ void f2_kernel(const float* __restrict__ f1b, const float* __restrict__ W,
                          const float* __restrict__ bias, float* __restrict__ out) {
  int idx = blockIdx.x * 256 + threadIdx.x;   // 36864
  int n = idx % 144;
  int t = (idx / 144) % 32;
  int b = idx / (144 * 32);
  float acc = bias[n];
  size_t fb = (size_t)(b * 32 + t) * 128;
  const float* wr = W + n * 128;
  #pragma unroll 4
  for (int k = 0; k < 128; ++k) acc += f1b[fb + k] * wr[k];
  out[idx] = acc;
}

extern "C" void kernel_launch(void* const* d_in, const int* in_sizes, int n_in,
                              void* d_out, int out_size, void* d_ws, size_t ws_size,
                              hipStream_t stream) {
  const float* input_tensor = (const float*)d_in[0];
  const float* mask_    = (const float*)d_in[1];
  const float* input_bw = (const float*)d_in[2];
  const float* mask_bw  = (const float*)d_in[3];
  const float* y_in     = (const float*)d_in[4];
  const float* ymask    = (const float*)d_in[5];
  const float* ws_p = (const float*)d_in[6];
  const float* bs_p = (const float*)d_in[7];
  const float* wc_p = (const float*)d_in[8];
  const float* bc_p = (const float*)d_in[9];
  const float* nv1 = (const float*)d_in[10];
  const float* nv2 = (const float*)d_in[11];
  const float* Wih_fw = (const float*)d_in[12];
  const float* Whh_fw = (const float*)d_in[13];
  const float* bih_fw = (const float*)d_in[14];
  const float* bhh_fw = (const float*)d_in[15];
  const float* Wih_bw = (const float*)d_in[16];
  const float* Whh_bw = (const float*)d_in[17];
  const float* bih_bw = (const float*)d_in[18];
  const float* bhh_bw = (const float*)d_in[19];
  const float* Wg   = (const float*)d_in[20];
  const float* bg   = (const float*)d_in[21];
  const float* gam  = (const float*)d_in[22];
  const float* bet  = (const float*)d_in[23];
  const float* W_end1 = (const float*)d_in[24];
  const float* b_end1 = (const float*)d_in[25];
  const float* W_end2 = (const float*)d_in[26];
  const float* b_end2 = (const float*)d_in[27];
  const float* W_lo = (const float*)d_in[28];
  const float* b_lo = (const float*)d_in[29];
  const float* W_f1 = (const float*)d_in[30];
  const float* b_f1 = (const float*)d_in[31];
  const float* W_f2 = (const float*)d_in[32];
  const float* b_f2 = (const float*)d_in[33];

  char* base = (char*)d_ws;
  size_t off = 0;
  auto alloc = [&](size_t bytes) -> char* {
    char* p = base + off;
    off += (bytes + 255) & ~(size_t)255;
    return p;
  };
  float* adp   = (float*)alloc(144 * 144 * 4);
  unsigned short* Weffpk = (unsigned short*)alloc((size_t)2 * 2654208 * 2);  // 10.6 MB
  float* beff  = (float*)alloc(2 * G4_ * 4);
  unsigned short* acatf  = (unsigned short*)alloc((size_t)2 * 73728 * 2);
  float* GxF   = (float*)alloc((size_t)32 * 73728 * 4);   // 9.44 MB
  float* GxB   = (float*)alloc((size_t)32 * 73728 * 4);
  char*  zreg  = alloc(6 * 147456 + 3 * 73728);            // h bf16 bufs + c bufs (zeroed)
  float* hsF   = (float*)alloc((size_t)589824 * 4);
  float* hsB   = (float*)alloc((size_t)589824 * 4);
  float* hsL   = (float*)alloc((size_t)294912 * 4);
  float* gin   = (float*)alloc((size_t)589824 * 4);
  float* x1b   = (float*)alloc((size_t)589824 * 4);
  float* x2b   = (float*)alloc((size_t)589824 * 4);
  float* out0  = (float*)alloc((size_t)589824 * 4);
  float* out1  = (float*)alloc((size_t)294912 * 4);
  unsigned short* xbf = (unsigned short*)alloc((size_t)294912 * 2);
  float* tmp1  = (float*)alloc((size_t)294912 * 4);
  float* tmp2  = (float*)alloc((size_t)589824 * 4);
  float* out3  = (float*)alloc((size_t)36864 * 4);
  float* f1b   = (float*)alloc((size_t)32768 * 4);
  unsigned short* P0 = (unsigned short*)alloc((size_t)2654208 * 8 * 2);  // 42.5 MB
  unsigned short* P1 = (unsigned short*)alloc((size_t)2654208 * 8 * 2);

  unsigned short* hbfF[2] = {(unsigned short*)zreg, (unsigned short*)(zreg + 147456)};
  unsigned short* hbfB[2] = {(unsigned short*)(zreg + 2 * 147456), (unsigned short*)(zreg + 3 * 147456)};
  unsigned short* hbfL[2] = {(unsigned short*)(zreg + 4 * 147456), (unsigned short*)(zreg + 5 * 147456)};
  float* cF = (float*)(zreg + 6 * 147456);
  float* cB = (float*)(zreg + 6 * 147456 + 73728);
  float* cL = (float*)(zreg + 6 * 147456 + 2 * 73728);

  hipMemsetAsync(zreg, 0, 6 * 147456 + 3 * 73728, stream);

  adp_kernel<<<144, 256, 0, stream>>>(nv1, nv2, adp);
  eff_weights<<<dim3(G4_, 2), 256, 0, stream>>>(Wih_fw, Wih_bw, bih_fw, bhh_fw, bih_bw, bhh_bw,
                                                ws_p, bs_p, wc_p, bc_p, Weffpk, beff);
  build_acat_frag<<<72, 256, 0, stream>>>(input_tensor, mask_, input_bw, mask_bw, acatf);
  gemm_frag<<<dim3(576, 4), 64, 0, stream>>>(acatf, Weffpk, beff, nullptr, GxF, 9);
  gemm_frag<<<dim3(576, 4), 64, 0, stream>>>(acatf + 73728, Weffpk + 2654208, beff + G4_, nullptr, GxB, 9);
  pack_whh<<<10368, 256, 0, stream>>>(Whh_fw, P0);
  pack_whh<<<10368, 256, 0, stream>>>(Whh_bw, P1);

  // ---- layer-0 scan (fw + bw concurrently) ----
  for (int t = 0; t < 32; ++t) {
    lstm_mfma<<<dim3(144, 2), 256, 0, stream>>>(
        P0, P1, GxF, GxB,
        hbfF[t & 1], hbfB[t & 1], hbfF[(t + 1) & 1], hbfB[(t + 1) & 1],
        cF, cB, hsF, hsB, t, 32);
  }

  combine_tanh<<<2304, 256, 0, stream>>>(hsF, hsB, gin, 32, 589824);
  gc1<<<2304, 256, 0, stream>>>(gin, adp, x1b, 32, 589824);
  gc1<<<2304, 256, 0, stream>>>(x1b, adp, x2b, 32, 589824);
  gc_out<<<2304, 256, 0, stream>>>(gin, x1b, x2b, Wg, bg, nullptr, out0, 32, 589824);
  bn_xt<<<16, 256, 0, stream>>>(out0, gam, bet, xbf);

  const size_t WL1_off = (size_t)G4_ * HN_;
  pack_whh<<<10368, 256, 0, stream>>>(Wih_fw + WL1_off, P1);   // layer-1 input weights
  gemm_frag<<<dim3(576, 2), 64, 0, stream>>>(xbf, P1, bih_fw + G4_, bhh_fw + G4_, GxF, 72);
  pack_whh<<<10368, 256, 0, stream>>>(Whh_fw + WL1_off, P0);   // layer-1 recurrent weights

  // ---- layer-1 scan ----
  for (int t = 0; t < 16; ++t) {
    lstm_mfma<<<dim3(144, 1), 256, 0, stream>>>(
        P0, P0, GxF, GxF,
        hbfL[t & 1], hbfL[t & 1], hbfL[(t + 1) & 1], hbfL[(t + 1) & 1],
        cL, cL, hsL, hsL, t, 16);
  }

  combine_tanh<<<1152, 256, 0, stream>>>(hsL, nullptr, gin, 16, 294912);
  gc1<<<1152, 256, 0, stream>>>(gin, adp, x1b, 16, 294912);
  gc1<<<1152, 256, 0, stream>>>(x1b, adp, x2b, 16, 294912);
  gc_out<<<1152, 256, 0, stream>>>(gin, x1b, x2b, Wg + 16 * 48, bg + 16, out0, out1, 16, 294912);

  e1_kernel<<<1152, 256, 0, stream>>>(out1, W_end1, b_end1, tmp1);
  e2_kernel<<<2304, 256, 0, stream>>>(tmp1, W_end2, b_end2, tmp2);
  e3_kernel<<<144, 256, 0, stream>>>(tmp2, W_lo, b_lo, out3);
  f1_kernel<<<128, 256, 0, stream>>>(out3, y_in, ymask, W_f1, b_f1, f1b);
  f2_kernel<<<144, 256, 0, stream>>>(f1b, W_f2, b_f2, (float*)d_out);
}